// Round 4
// baseline (296.412 us; speedup 1.0000x reference)
//
#include <hip/hip_runtime.h>
#include <stdint.h>

// Problem constants (fixed by reference setup_inputs)
#define BB 8
#define SS 2048
#define DD 2048
#define EE 8
#define CHUNKS 256
#define ROWS 8              // SS / CHUNKS
#define NBLK (BB * CHUNKS)  // 2048 blocks
#define AUX  (NBLK * 9)     // float offset of W-stat aux region in pbuf

typedef float f4 __attribute__((ext_vector_type(4)));

// Arrival counter. Module-scope device global: initialized to 0 at load,
// NOT poisoned by the harness (it lives in the module, not d_ws), and the
// unique last block resets it to 0 each iteration -> invariant holds across
// graph replays.
__device__ unsigned g_ctr = 0;

// Single fused kernel, no grid barrier:
//  - all 2048 blocks: stream 8 rows of x -> column sums -> dot with W (L2-hot)
//    -> 9 partials to pbuf; block 0 additionally reduces W sum/sumsq -> aux.
//  - arrival counter (device-scope release fence + atomicAdd); every block
//    except the last exits.
//  - last block: acquire fence, reduce 2048 records + aux W stats, scores,
//    softmax, top-2, outputs. Counter reset to 0.
__global__ __launch_bounds__(256) void k_router(const float* __restrict__ x,
                                                const float* __restrict__ W,
                                                const float* __restrict__ gain,
                                                const float* __restrict__ istd,
                                                const float* __restrict__ noise,
                                                float* __restrict__ pbuf,
                                                float* __restrict__ out) {
    const int t = threadIdx.x;
    const int bid = blockIdx.x;
    const int b = bid >> 8;              // / CHUNKS
    const int chunk = bid & (CHUNKS - 1);
    const int d0 = t * 8;                // 256 threads * 8 floats = full D row

    const float* xp = x + ((size_t)b * SS + (size_t)chunk * ROWS) * DD + d0;

    // ---- column sums over 8 rows, 2 groups of 4 rows (8 loads in flight)
    f4 s0 = {0.f, 0.f, 0.f, 0.f}, s1 = {0.f, 0.f, 0.f, 0.f};
#pragma unroll
    for (int gq = 0; gq < 2; ++gq) {
        const float* p = xp + (size_t)gq * 4 * DD;
        f4 a0 = *(const f4*)(p);
        f4 b0 = *(const f4*)(p + 4);
        f4 a1 = *(const f4*)(p + DD);
        f4 b1 = *(const f4*)(p + DD + 4);
        f4 a2 = *(const f4*)(p + 2 * DD);
        f4 b2 = *(const f4*)(p + 2 * DD + 4);
        f4 a3 = *(const f4*)(p + 3 * DD);
        f4 b3 = *(const f4*)(p + 3 * DD + 4);
        s0 += a0; s1 += b0;
        s0 += a1; s1 += b1;
        s0 += a2; s1 += b2;
        s0 += a3; s1 += b3;
    }

    // ---- epilogue: 9 partials = 8 expert dots + total x sum
    float vals[9];
    vals[8] = s0[0] + s0[1] + s0[2] + s0[3] + s1[0] + s1[1] + s1[2] + s1[3];
    float wsv[8], wqv[8];   // per-expert W sum / sumsq partials (block 0 uses)
#pragma unroll
    for (int e = 0; e < 8; ++e) {
        f4 wa = *(const f4*)(W + e * DD + d0);
        f4 wb = *(const f4*)(W + e * DD + d0 + 4);
        float acc = 0.f;
#pragma unroll
        for (int j = 0; j < 4; ++j) acc = fmaf(s0[j], wa[j], acc);
#pragma unroll
        for (int j = 0; j < 4; ++j) acc = fmaf(s1[j], wb[j], acc);
        vals[e] = acc;
        float ws = wa[0] + wa[1] + wa[2] + wa[3] + wb[0] + wb[1] + wb[2] + wb[3];
        float wq = 0.f;
#pragma unroll
        for (int j = 0; j < 4; ++j) wq = fmaf(wa[j], wa[j], wq);
#pragma unroll
        for (int j = 0; j < 4; ++j) wq = fmaf(wb[j], wb[j], wq);
        wsv[e] = ws;
        wqv[e] = wq;
    }

    // ---- wave butterfly reduce of the 9 partials, then cross-wave via LDS
#pragma unroll
    for (int off = 32; off >= 1; off >>= 1) {
#pragma unroll
        for (int j = 0; j < 9; ++j) vals[j] += __shfl_xor(vals[j], off, 64);
    }

    __shared__ float lw[4][9];
    const int lane = t & 63, wid = t >> 6;
    if (lane == 0) {
#pragma unroll
        for (int j = 0; j < 9; ++j) lw[wid][j] = vals[j];
    }
    __syncthreads();
    if (t < 9) {
        pbuf[bid * 9 + t] = lw[0][t] + lw[1][t] + lw[2][t] + lw[3][t];
    }

    // ---- block 0 only: W row stats (covers all 2048 cols x 8 experts)
    if (bid == 0) {
#pragma unroll
        for (int off = 32; off >= 1; off >>= 1) {
#pragma unroll
            for (int e = 0; e < 8; ++e) {
                wsv[e] += __shfl_xor(wsv[e], off, 64);
                wqv[e] += __shfl_xor(wqv[e], off, 64);
            }
        }
        __shared__ float lw2[4][16];
        if (lane == 0) {
#pragma unroll
            for (int e = 0; e < 8; ++e) {
                lw2[wid][e] = wsv[e];
                lw2[wid][8 + e] = wqv[e];
            }
        }
        __syncthreads();
        if (t < 16) {
            pbuf[AUX + t] = lw2[0][t] + lw2[1][t] + lw2[2][t] + lw2[3][t];
        }
    }

    // ---- arrival: device-scope release, then count. All but last block exit.
    __syncthreads();                    // drains this block's global stores (vmcnt 0)
    __shared__ int s_last;
    if (t == 0) {
        __threadfence();                // release: L2 writeback of our partials
        unsigned old = atomicAdd(&g_ctr, 1u);
        s_last = (old == (unsigned)(NBLK - 1)) ? 1 : 0;
    }
    __syncthreads();
    if (!s_last) return;

    // ================= last block: finish =================
    if (t == 0) g_ctr = 0;              // reset for next iteration (visible at kernel end)
    __threadfence();                    // acquire: invalidate L1/L2 so cross-XCD
                                        // partials are fetched fresh from L3/HBM

    const int l = t & 31;
    const int g = t >> 5;               // batch index in phase A

    __shared__ float sdot[BB][9];
    __shared__ float smean[EE], sscale[EE];

    // W stats from aux (already fully reduced by block 0)
    if (t < EE) {
        const float s = pbuf[AUX + t];
        const float q = pbuf[AUX + 8 + t];
        const float mean = s / (float)DD;
        float var = (q - (float)DD * mean * mean) / (float)(DD - 1);
        var = fmaxf(var, 0.f);
        const float stdv = sqrtf(var) + 1e-5f;   // torch-style unbiased std + EPS
        smean[t] = mean;
        sscale[t] = istd[t] / stdv * gain[t];
    }

    // Phase A: thread t owns records [t*8, t*8+8) (72 floats = 18 f4), all in
    // batch g = t>>5; tree-reduce across its 32-thread group.
    float sums[9] = {0.f, 0.f, 0.f, 0.f, 0.f, 0.f, 0.f, 0.f, 0.f};
    {
        const f4* pa = (const f4*)(pbuf + (size_t)t * 72);
#pragma unroll
        for (int i = 0; i < 18; ++i) {
            f4 v = pa[i];
#pragma unroll
            for (int j = 0; j < 4; ++j) sums[(i * 4 + j) % 9] += v[j];
        }
    }
#pragma unroll
    for (int off = 16; off >= 1; off >>= 1) {
#pragma unroll
        for (int j = 0; j < 9; ++j) sums[j] += __shfl_xor(sums[j], off, 64);
    }
    if (l < 9) sdot[g][l] = sums[l];
    __syncthreads();

    // Phase C: one thread per batch row
    if (t < BB) {
        const int bb = t;
        const float xtot = sdot[bb][8];
        float p[EE];
        float m = -1e30f;
#pragma unroll
        for (int e = 0; e < EE; ++e) {
            float sc = sscale[e] * (sdot[bb][e] - smean[e] * xtot) * (1.f / (float)SS)
                     + noise[bb * EE + e];
            p[e] = sc;
            m = fmaxf(m, sc);
        }
        float sum = 0.f;
#pragma unroll
        for (int e = 0; e < EE; ++e) { p[e] = __expf(p[e] - m); sum += p[e]; }
        const float inv = 1.f / sum;
#pragma unroll
        for (int e = 0; e < EE; ++e) p[e] *= inv;

        // top-2, ties -> lowest index first (strict >, ascending scan)
        int i1 = 0;
#pragma unroll
        for (int e = 1; e < EE; ++e) if (p[e] > p[i1]) i1 = e;
        int i2 = (i1 == 0) ? 1 : 0;
#pragma unroll
        for (int e = 0; e < EE; ++e) if (e != i1 && p[e] > p[i2]) i2 = e;

        // combine tensor [B,E]
#pragma unroll
        for (int e = 0; e < EE; ++e) {
            float v = (e == i1) ? p[i1] : ((e == i2) ? p[i2] : 0.f);
            out[bb * EE + e] = v;
        }
        // indices [B,2] as numeric values
        out[64 + bb * 2 + 0] = (float)i1;
        out[64 + bb * 2 + 1] = (float)i2;
        // topk gate scores [B,2]
        out[80 + bb * 2 + 0] = p[i1];
        out[80 + bb * 2 + 1] = p[i2];
    }
}

extern "C" void kernel_launch(void* const* d_in, const int* in_sizes, int n_in,
                              void* d_out, int out_size, void* d_ws, size_t ws_size,
                              hipStream_t stream) {
    const float* x     = (const float*)d_in[0];
    const float* W     = (const float*)d_in[1];
    const float* gain  = (const float*)d_in[2];
    const float* istd  = (const float*)d_in[3];
    const float* noise = (const float*)d_in[4];
    // d_in[5] = top_k (==2) — hardcoded per reference.

    float* pbuf = (float*)d_ws;          // NBLK*9 + 16 floats ~= 74 KB
    float* out  = (float*)d_out;         // 96 fp32

    k_router<<<dim3(NBLK), dim3(256), 0, stream>>>(x, W, gain, istd, noise, pbuf, out);
}

// Round 5
// 207.684 us; speedup vs baseline: 1.4272x; 1.4272x over previous
//
#include <hip/hip_runtime.h>
#include <stdint.h>

// Problem constants (fixed by reference setup_inputs)
#define BB 8
#define SS 2048
#define DD 2048
#define EE 8
#define CHUNKS 128          // chunks per batch
#define ROWS 16             // rows per chunk (SS / CHUNKS)
#define NBLK (BB * CHUNKS)  // 1024 blocks

typedef float f4 __attribute__((ext_vector_type(4)));

// Arrival counter. Module-scope device global: zero-initialized at module load,
// NOT poisoned by the harness. The unique last block resets it to 0; the
// kernel-end flush publishes the reset for the next iteration (validated R4).
__device__ unsigned g_ctr = 0;

// Single fused kernel — NO fences anywhere (R4 lesson: per-block __threadfence
// costs ~77 ns of serialized L2 writeback; 2048 of them = 157 us).
// All cross-block communication is atomic-only:
//   publish: atomicExch (coherence-point write, poison-safe)
//   order:   consume the returned value (forces s_waitcnt) BEFORE the counter
//   consume: returning atomicOr(ptr, 0) == coherent deterministic read
__global__ __launch_bounds__(256) void k_router(const float* __restrict__ x,
                                                const float* __restrict__ W,
                                                const float* __restrict__ gain,
                                                const float* __restrict__ istd,
                                                const float* __restrict__ noise,
                                                float* __restrict__ pbuf,
                                                float* __restrict__ out) {
    const int t = threadIdx.x;
    const int bid = blockIdx.x;
    const int b = bid >> 7;              // / CHUNKS
    const int chunk = bid & (CHUNKS - 1);
    const int d0 = t * 8;                // 256 threads * 8 floats = full D row

    const float* xp = x + ((size_t)b * SS + (size_t)chunk * ROWS) * DD + d0;

    // ---- Phase 1: column sums over 16 rows, 4 pipelined groups of 4 rows
    f4 s0 = {0.f, 0.f, 0.f, 0.f}, s1 = {0.f, 0.f, 0.f, 0.f};
#pragma unroll
    for (int gq = 0; gq < 4; ++gq) {
        const float* p = xp + (size_t)gq * 4 * DD;
        f4 a0 = *(const f4*)(p);
        f4 b0 = *(const f4*)(p + 4);
        f4 a1 = *(const f4*)(p + DD);
        f4 b1 = *(const f4*)(p + DD + 4);
        f4 a2 = *(const f4*)(p + 2 * DD);
        f4 b2 = *(const f4*)(p + 2 * DD + 4);
        f4 a3 = *(const f4*)(p + 3 * DD);
        f4 b3 = *(const f4*)(p + 3 * DD + 4);
        s0 += a0; s1 += b0;
        s0 += a1; s1 += b1;
        s0 += a2; s1 += b2;
        s0 += a3; s1 += b3;
    }

    // ---- epilogue: 9 partials = 8 expert dots (W is L2-hot) + total x sum
    float vals[9];
    vals[8] = s0[0] + s0[1] + s0[2] + s0[3] + s1[0] + s1[1] + s1[2] + s1[3];
#pragma unroll
    for (int e = 0; e < 8; ++e) {
        f4 wa = *(const f4*)(W + e * DD + d0);
        f4 wb = *(const f4*)(W + e * DD + d0 + 4);
        float acc = 0.f;
#pragma unroll
        for (int j = 0; j < 4; ++j) acc = fmaf(s0[j], wa[j], acc);
#pragma unroll
        for (int j = 0; j < 4; ++j) acc = fmaf(s1[j], wb[j], acc);
        vals[e] = acc;
    }

    // ---- wave butterfly reduce of the 9 partials, then cross-wave via LDS
#pragma unroll
    for (int off = 32; off >= 1; off >>= 1) {
#pragma unroll
        for (int j = 0; j < 9; ++j) vals[j] += __shfl_xor(vals[j], off, 64);
    }

    __shared__ float lw[4][9];
    const int lane = t & 63, wid = t >> 6;
    if (lane == 0) {
#pragma unroll
        for (int j = 0; j < 9; ++j) lw[wid][j] = vals[j];
    }
    __syncthreads();

    // ---- publish the 9 partials via atomicExch; consume the returns so the
    // wave's s_waitcnt completes (record globally visible) BEFORE the barrier.
    if (t < 9) {
        float v = lw[0][t] + lw[1][t] + lw[2][t] + lw[3][t];
        float old = atomicExch(&pbuf[bid * 9 + t], v);
        asm volatile("" :: "v"(old));   // keep-alive: forces completion wait
    }
    __syncthreads();

    // ---- arrival count; every block except the last exits
    __shared__ unsigned s_old;
    if (t == 0) s_old = atomicAdd(&g_ctr, 1u);
    __syncthreads();
    if (s_old != (unsigned)(NBLK - 1)) return;

    // ================= last block: finish =================
    if (t == 0) g_ctr = 0;   // published by kernel-end flush (validated R4)

    const int l = t & 31;
    const int g = t >> 5;    // group 0..7: batch idx in phase A, expert idx in phase B

    __shared__ float sdot[BB][9];
    __shared__ float smean[EE], sscale[EE];

    // Phase A: thread t owns records [t*4, t*4+4) — 36 floats, all in batch
    // g = t>>5 (128 records per batch). Coherent deterministic reads via
    // returning atomicOr(ptr, 0). Grouped 9-at-a-time, all indices static.
    float sums[9] = {0.f, 0.f, 0.f, 0.f, 0.f, 0.f, 0.f, 0.f, 0.f};
    {
        unsigned* pb = (unsigned*)pbuf;
        const int base = t * 36;
#pragma unroll
        for (int r = 0; r < 4; ++r) {
            float tmp[9];
#pragma unroll
            for (int j = 0; j < 9; ++j) {
                unsigned u = atomicOr(pb + base + r * 9 + j, 0u);
                tmp[j] = __uint_as_float(u);
            }
#pragma unroll
            for (int j = 0; j < 9; ++j) sums[j] += tmp[j];
        }
    }

    // Phase B (overlaps with phase-A atomics in flight): W row stats.
    // W is a read-only kernel input -> plain loads are coherent.
    {
        float s = 0.f, q = 0.f;
        const f4* wp = (const f4*)(W + (size_t)g * DD + l * 64);
#pragma unroll
        for (int i = 0; i < 16; ++i) {
            f4 v = wp[i];
#pragma unroll
            for (int j = 0; j < 4; ++j) { s += v[j]; q = fmaf(v[j], v[j], q); }
        }
#pragma unroll
        for (int off = 16; off >= 1; off >>= 1) {
            s += __shfl_xor(s, off, 64);
            q += __shfl_xor(q, off, 64);
        }
        if (l == 0) {
            const float mean = s / (float)DD;
            float var = (q - (float)DD * mean * mean) / (float)(DD - 1);
            var = fmaxf(var, 0.f);
            const float stdv = sqrtf(var) + 1e-5f;   // torch-style unbiased std + EPS
            smean[g] = mean;
            sscale[g] = istd[g] / stdv * gain[g];
        }
    }

    // finish phase-A reduction across the 32-thread group (covers one batch)
#pragma unroll
    for (int off = 16; off >= 1; off >>= 1) {
#pragma unroll
        for (int j = 0; j < 9; ++j) sums[j] += __shfl_xor(sums[j], off, 64);
    }
    if (l < 9) sdot[g][l] = sums[l];
    __syncthreads();

    // Phase C: one thread per batch row
    if (t < BB) {
        const int bb = t;
        const float xtot = sdot[bb][8];
        float p[EE];
        float m = -1e30f;
#pragma unroll
        for (int e = 0; e < EE; ++e) {
            float sc = sscale[e] * (sdot[bb][e] - smean[e] * xtot) * (1.f / (float)SS)
                     + noise[bb * EE + e];
            p[e] = sc;
            m = fmaxf(m, sc);
        }
        float sum = 0.f;
#pragma unroll
        for (int e = 0; e < EE; ++e) { p[e] = __expf(p[e] - m); sum += p[e]; }
        const float inv = 1.f / sum;
#pragma unroll
        for (int e = 0; e < EE; ++e) p[e] *= inv;

        // top-2, ties -> lowest index first (strict >, ascending scan)
        int i1 = 0;
#pragma unroll
        for (int e = 1; e < EE; ++e) if (p[e] > p[i1]) i1 = e;
        int i2 = (i1 == 0) ? 1 : 0;
#pragma unroll
        for (int e = 0; e < EE; ++e) if (e != i1 && p[e] > p[i2]) i2 = e;

        // combine tensor [B,E]
#pragma unroll
        for (int e = 0; e < EE; ++e) {
            float v = (e == i1) ? p[i1] : ((e == i2) ? p[i2] : 0.f);
            out[bb * EE + e] = v;
        }
        // indices [B,2] as numeric values
        out[64 + bb * 2 + 0] = (float)i1;
        out[64 + bb * 2 + 1] = (float)i2;
        // topk gate scores [B,2]
        out[80 + bb * 2 + 0] = p[i1];
        out[80 + bb * 2 + 1] = p[i2];
    }
}

extern "C" void kernel_launch(void* const* d_in, const int* in_sizes, int n_in,
                              void* d_out, int out_size, void* d_ws, size_t ws_size,
                              hipStream_t stream) {
    const float* x     = (const float*)d_in[0];
    const float* W     = (const float*)d_in[1];
    const float* gain  = (const float*)d_in[2];
    const float* istd  = (const float*)d_in[3];
    const float* noise = (const float*)d_in[4];
    // d_in[5] = top_k (==2) — hardcoded per reference.

    float* pbuf = (float*)d_ws;          // NBLK*9 floats = 36 KB
    float* out  = (float*)d_out;         // 96 fp32

    k_router<<<dim3(NBLK), dim3(256), 0, stream>>>(x, W, gain, istd, noise, pbuf, out);
}

// Round 6
// 199.447 us; speedup vs baseline: 1.4862x; 1.0413x over previous
//
#include <hip/hip_runtime.h>
#include <stdint.h>

// Problem constants (fixed by reference setup_inputs)
#define BB 8
#define SS 2048
#define DD 2048
#define EE 8
#define CHUNKS 256
#define ROWS 8              // SS / CHUNKS
#define NBLK (BB * CHUNKS)  // 2048 blocks
#define AUX  (NBLK * 9)     // float offset of W-stat aux region in pbuf

typedef float f4 __attribute__((ext_vector_type(4)));

// Kernel 1: stream x (fp32). Per block = one (b, chunk of 8 rows).
// COALESCING: thread t owns cols [t*4, t*4+4) and [1024+t*4, 1024+t*4+4),
// so every global_load_dwordx4 is lane-contiguous (64 lanes x 16 B = 1 KiB
// per instruction) — R3's t*8 layout was a 32B-stride interleave (half-line
// utilization per instruction).
// Epilogue: dot with W (L2-hot) -> 9 partials; block 0 additionally reduces
// per-expert sum/sumsq of W (it already holds all of W in fragments) -> aux.
__global__ __launch_bounds__(256) void k_partial(const float* __restrict__ x,
                                                 const float* __restrict__ W,
                                                 float* __restrict__ pout) {
    const int t = threadIdx.x;
    const int bid = blockIdx.x;
    const int b = bid >> 8;              // / CHUNKS
    const int chunk = bid & (CHUNKS - 1);
    const int c0 = t * 4;                // first owned f4 column
    const int c1 = 1024 + t * 4;         // second owned f4 column

    const float* xp = x + ((size_t)b * SS + (size_t)chunk * ROWS) * DD;

    // ---- column sums over 8 rows, 2 groups of 4 rows (8 loads in flight)
    f4 s0 = {0.f, 0.f, 0.f, 0.f}, s1 = {0.f, 0.f, 0.f, 0.f};
#pragma unroll
    for (int gq = 0; gq < 2; ++gq) {
        const float* p = xp + (size_t)gq * 4 * DD;
        f4 a0 = *(const f4*)(p + c0);
        f4 b0 = *(const f4*)(p + c1);
        f4 a1 = *(const f4*)(p + DD + c0);
        f4 b1 = *(const f4*)(p + DD + c1);
        f4 a2 = *(const f4*)(p + 2 * DD + c0);
        f4 b2 = *(const f4*)(p + 2 * DD + c1);
        f4 a3 = *(const f4*)(p + 3 * DD + c0);
        f4 b3 = *(const f4*)(p + 3 * DD + c1);
        s0 += a0; s1 += b0;
        s0 += a1; s1 += b1;
        s0 += a2; s1 += b2;
        s0 += a3; s1 += b3;
    }

    // ---- epilogue: 9 partials = 8 expert dots + total x sum
    float vals[9];
    vals[8] = s0[0] + s0[1] + s0[2] + s0[3] + s1[0] + s1[1] + s1[2] + s1[3];
    float wsv[8], wqv[8];   // per-expert W sum / sumsq partials (block 0 uses)
#pragma unroll
    for (int e = 0; e < 8; ++e) {
        f4 wa = *(const f4*)(W + e * DD + c0);
        f4 wb = *(const f4*)(W + e * DD + c1);
        float acc = 0.f;
#pragma unroll
        for (int j = 0; j < 4; ++j) acc = fmaf(s0[j], wa[j], acc);
#pragma unroll
        for (int j = 0; j < 4; ++j) acc = fmaf(s1[j], wb[j], acc);
        vals[e] = acc;
        float ws = wa[0] + wa[1] + wa[2] + wa[3] + wb[0] + wb[1] + wb[2] + wb[3];
        float wq = 0.f;
#pragma unroll
        for (int j = 0; j < 4; ++j) wq = fmaf(wa[j], wa[j], wq);
#pragma unroll
        for (int j = 0; j < 4; ++j) wq = fmaf(wb[j], wb[j], wq);
        wsv[e] = ws;
        wqv[e] = wq;
    }

    // ---- wave butterfly reduce of the 9 partials, then cross-wave via LDS
#pragma unroll
    for (int off = 32; off >= 1; off >>= 1) {
#pragma unroll
        for (int j = 0; j < 9; ++j) vals[j] += __shfl_xor(vals[j], off, 64);
    }

    __shared__ float lw[4][9];
    const int lane = t & 63, wid = t >> 6;
    if (lane == 0) {
#pragma unroll
        for (int j = 0; j < 9; ++j) lw[wid][j] = vals[j];
    }
    __syncthreads();
    if (t < 9) {
        pout[bid * 9 + t] = lw[0][t] + lw[1][t] + lw[2][t] + lw[3][t];
    }

    // ---- block 0 only: finish W row stats (256 threads x 8 cols = all 2048)
    if (bid == 0) {
#pragma unroll
        for (int off = 32; off >= 1; off >>= 1) {
#pragma unroll
            for (int e = 0; e < 8; ++e) {
                wsv[e] += __shfl_xor(wsv[e], off, 64);
                wqv[e] += __shfl_xor(wqv[e], off, 64);
            }
        }
        __shared__ float lw2[4][16];
        if (lane == 0) {
#pragma unroll
            for (int e = 0; e < 8; ++e) {
                lw2[wid][e] = wsv[e];
                lw2[wid][8 + e] = wqv[e];
            }
        }
        __syncthreads();
        if (t < 16) {
            pout[AUX + t] = lw2[0][t] + lw2[1][t] + lw2[2][t] + lw2[3][t];
        }
    }
}

// Kernel 2: single block. W stats arrive pre-reduced in aux (16 floats).
// Phase A: reduce 2048 partial records (9 floats each, 72 KB): thread t owns
//          8 consecutive records (18 f4 loads, same batch g = t>>5),
//          then 5-stage shfl_xor tree across its 32-thread group.
// Phase C: 8 threads: scores -> softmax -> top2 -> outputs.
__global__ __launch_bounds__(256) void k_finish(const float* __restrict__ pin,
                                                const float* __restrict__ gain,
                                                const float* __restrict__ istd,
                                                const float* __restrict__ noise,
                                                float* __restrict__ out) {
    const int t = threadIdx.x;
    const int l = t & 31;
    const int g = t >> 5;   // batch index in phase A

    __shared__ float sdot[BB][9];
    __shared__ float smean[EE], sscale[EE];

    // ---- W stats from aux (already fully reduced by k_partial block 0)
    if (t < EE) {
        const float s = pin[AUX + t];
        const float q = pin[AUX + 8 + t];
        const float mean = s / (float)DD;
        float var = (q - (float)DD * mean * mean) / (float)(DD - 1);
        var = fmaxf(var, 0.f);
        const float stdv = sqrtf(var) + 1e-5f;   // torch-style unbiased std + EPS
        smean[t] = mean;
        sscale[t] = istd[t] / stdv * gain[t];
    }

    // ---- Phase A
    float sums[9] = {0.f, 0.f, 0.f, 0.f, 0.f, 0.f, 0.f, 0.f, 0.f};
    {
        const f4* pa = (const f4*)(pin + (size_t)t * 72);
#pragma unroll
        for (int i = 0; i < 18; ++i) {
            f4 v = pa[i];
#pragma unroll
            for (int j = 0; j < 4; ++j) sums[(i * 4 + j) % 9] += v[j];
        }
    }
#pragma unroll
    for (int off = 16; off >= 1; off >>= 1) {
#pragma unroll
        for (int j = 0; j < 9; ++j) sums[j] += __shfl_xor(sums[j], off, 64);
    }
    if (l < 9) sdot[g][l] = sums[l];
    __syncthreads();

    // ---- Phase C: one thread per batch row
    if (t < BB) {
        const int b = t;
        const float xtot = sdot[b][8];
        float p[EE];
        float m = -1e30f;
#pragma unroll
        for (int e = 0; e < EE; ++e) {
            float sc = sscale[e] * (sdot[b][e] - smean[e] * xtot) * (1.f / (float)SS)
                     + noise[b * EE + e];
            p[e] = sc;
            m = fmaxf(m, sc);
        }
        float sum = 0.f;
#pragma unroll
        for (int e = 0; e < EE; ++e) { p[e] = __expf(p[e] - m); sum += p[e]; }
        const float inv = 1.f / sum;
#pragma unroll
        for (int e = 0; e < EE; ++e) p[e] *= inv;

        // top-2, ties -> lowest index first (strict >, ascending scan)
        int i1 = 0;
#pragma unroll
        for (int e = 1; e < EE; ++e) if (p[e] > p[i1]) i1 = e;
        int i2 = (i1 == 0) ? 1 : 0;
#pragma unroll
        for (int e = 0; e < EE; ++e) if (e != i1 && p[e] > p[i2]) i2 = e;

        // combine tensor [B,E]
#pragma unroll
        for (int e = 0; e < EE; ++e) {
            float v = (e == i1) ? p[i1] : ((e == i2) ? p[i2] : 0.f);
            out[b * EE + e] = v;
        }
        // indices [B,2] as numeric values
        out[64 + b * 2 + 0] = (float)i1;
        out[64 + b * 2 + 1] = (float)i2;
        // topk gate scores [B,2]
        out[80 + b * 2 + 0] = p[i1];
        out[80 + b * 2 + 1] = p[i2];
    }
}

extern "C" void kernel_launch(void* const* d_in, const int* in_sizes, int n_in,
                              void* d_out, int out_size, void* d_ws, size_t ws_size,
                              hipStream_t stream) {
    const float* x     = (const float*)d_in[0];
    const float* W     = (const float*)d_in[1];
    const float* gain  = (const float*)d_in[2];
    const float* istd  = (const float*)d_in[3];
    const float* noise = (const float*)d_in[4];
    // d_in[5] = top_k (==2) — hardcoded per reference.

    float* pbuf = (float*)d_ws;          // NBLK*9 + 16 floats ~= 74 KB
    float* out  = (float*)d_out;         // 96 fp32

    k_partial<<<dim3(NBLK), dim3(256), 0, stream>>>(x, W, pbuf);
    k_finish<<<dim3(1), dim3(256), 0, stream>>>(pbuf, gain, istd, noise, out);
}